// Round 3
// baseline (575.983 us; speedup 1.0000x reference)
//
#include <hip/hip_runtime.h>
#include <hip/hip_bf16.h>

typedef __hip_bfloat16 bf16;
typedef __attribute__((ext_vector_type(8))) short bfx8;
typedef __attribute__((ext_vector_type(4))) short bfx4;
typedef __attribute__((ext_vector_type(4))) float fx4;
typedef __attribute__((ext_vector_type(4))) int ix4;

#define KD 384   // inner K for both GEMMs
#define CH 384

__device__ __forceinline__ float bf2f(bf16 v) { return __bfloat162float(v); }
__device__ __forceinline__ bf16 f2bf(float v) { return __float2bfloat16(v); }
// pack two fp32 -> two bf16 (RNE) in one dword: low=x, high=y
__device__ __forceinline__ int pk2(float x, float y) {
    return (int)(((unsigned)__bfloat16_as_ushort(__float2bfloat16(y)) << 16) |
                 (unsigned)__bfloat16_as_ushort(__float2bfloat16(x)));
}

// ---------------------------------------------------------------------------
// GEMM: C[r, oc] = sum_k A[r,k] * B[oc,k] + bias[oc]   (A,B fp32 in memory,
// converted to bf16 in registers during LDS staging; fp32 MFMA accumulate)
// MODE 0: B = concat(q_w, kv_w); scatter-store bf16 to qkv natural layout
//         [b][g][m][dd]  (g=oc/64, dd=oc%64, b=r/4096, m=r%4096)
// MODE 1: A = gel (bf16!), B = proj_w; fp32 store [r][oc] to d_out
// 128x128 tile, 256 threads (4 waves, 2x2), 4x4 MFMA 16x16x32 per wave.
// ---------------------------------------------------------------------------
template <int MODE>
__global__ __launch_bounds__(256) void gemm_tile(
    const void* __restrict__ Av, const float* __restrict__ B0,
    const float* __restrict__ B1, const float* __restrict__ bias0,
    const float* __restrict__ bias1, void* __restrict__ outv)
{
    const int tid  = threadIdx.x;
    const int wave = tid >> 6, lane = tid & 63;
    const int n0 = blockIdx.x * 128;   // output-channel tile
    const int m0 = blockIdx.y * 128;   // row tile

    const float* Bsrc;
    const float* bsrc;
    int boff;
    if constexpr (MODE == 0) {
        if (n0 >= CH) { Bsrc = B1 + (size_t)(n0 - CH) * KD; bsrc = bias1; boff = n0 - CH; }
        else          { Bsrc = B0 + (size_t)n0 * KD;        bsrc = bias0; boff = n0; }
    } else {
        Bsrc = B0 + (size_t)n0 * KD; bsrc = bias0; boff = n0;
    }

    const int wm = (wave & 1) * 64, wn = (wave >> 1) * 64;
    const int r16 = lane & 15, quad = lane >> 4;
    const int lrow = tid >> 1;          // staging row 0..127
    const int lkh  = (tid & 1) * 16;    // staging k-half 0/16

    __shared__ bf16 As[128 * 32];
    __shared__ bf16 Bs[128 * 32];

    fx4 acc[4][4];
#pragma unroll
    for (int i = 0; i < 4; ++i)
#pragma unroll
        for (int j = 0; j < 4; ++j) acc[i][j] = (fx4){0.f, 0.f, 0.f, 0.f};

    for (int kt = 0; kt < KD; kt += 32) {
        // ---- load fp32 (or bf16 for MODE1 A) into regs, convert, stage ----
        ix4 apk0, apk1, bpk0, bpk1;
        if constexpr (MODE == 0) {
            const float* ap = (const float*)Av + (size_t)(m0 + lrow) * KD + kt + lkh;
            const fx4 a0 = *(const fx4*)(ap+0), a1 = *(const fx4*)(ap+4);
            const fx4 a2 = *(const fx4*)(ap+8), a3 = *(const fx4*)(ap+12);
            apk0 = (ix4){pk2(a0[0],a0[1]), pk2(a0[2],a0[3]), pk2(a1[0],a1[1]), pk2(a1[2],a1[3])};
            apk1 = (ix4){pk2(a2[0],a2[1]), pk2(a2[2],a2[3]), pk2(a3[0],a3[1]), pk2(a3[2],a3[3])};
        } else {
            // A is already bf16 (gel): straight 16B copy of 16 bf16
            const bf16* ap = (const bf16*)Av + (size_t)(m0 + lrow) * KD + kt + lkh;
            apk0 = ((const ix4*)(const void*)ap)[0];
            apk1 = ((const ix4*)(const void*)ap)[1];
        }
        {
            const float* bp = Bsrc + (size_t)lrow * KD + kt + lkh;
            const fx4 b0 = *(const fx4*)(bp+0), b1 = *(const fx4*)(bp+4);
            const fx4 b2 = *(const fx4*)(bp+8), b3 = *(const fx4*)(bp+12);
            bpk0 = (ix4){pk2(b0[0],b0[1]), pk2(b0[2],b0[3]), pk2(b1[0],b1[1]), pk2(b1[2],b1[3])};
            bpk1 = (ix4){pk2(b2[0],b2[1]), pk2(b2[2],b2[3]), pk2(b3[0],b3[1]), pk2(b3[2],b3[3])};
        }

        __syncthreads();  // readers done with previous tile
        {
            ix4* ad = (ix4*)(void*)(As + lrow * 32 + lkh);
            ad[0] = apk0; ad[1] = apk1;
            ix4* bd = (ix4*)(void*)(Bs + lrow * 32 + lkh);
            bd[0] = bpk0; bd[1] = bpk1;
        }
        __syncthreads();  // staged tile visible

        bfx8 af[4], bfr[4];
#pragma unroll
        for (int t = 0; t < 4; ++t) {
            af[t]  = *(const bfx8*)(const void*)(As + (wm + t * 16 + r16) * 32 + quad * 8);
            bfr[t] = *(const bfx8*)(const void*)(Bs + (wn + t * 16 + r16) * 32 + quad * 8);
        }
#pragma unroll
        for (int i = 0; i < 4; ++i)
#pragma unroll
            for (int j = 0; j < 4; ++j)
                acc[i][j] = __builtin_amdgcn_mfma_f32_16x16x32_bf16(
                    af[i], bfr[j], acc[i][j], 0, 0, 0);
    }

#pragma unroll
    for (int j = 0; j < 4; ++j) {
        const int oc_loc = wn + j * 16 + r16;
        const int oc = n0 + oc_loc;
        const float bv = bsrc[boff + oc_loc];
#pragma unroll
        for (int i = 0; i < 4; ++i) {
#pragma unroll
            for (int v = 0; v < 4; ++v) {
                const int r = m0 + wm + i * 16 + quad * 4 + v;
                const float val = acc[i][j][v] + bv;
                if constexpr (MODE == 0) {
                    const int bb = r >> 12, m = r & 4095;
                    const int g = oc >> 6, dd = oc & 63;
                    ((bf16*)outv)[(((size_t)bb * 18 + g) * 4096 + m) * 64 + dd] = f2bf(val);
                } else {
                    ((float*)outv)[(size_t)r * CH + oc] = val;
                }
            }
        }
    }
}

// ---------------------------------------------------------------------------
// fc: f_conv[b,o,n,dd] = fc_b[o] + sum_i fc_w[o,i] * qkv_flat[b][n*18+i][dd]
// stored as fconv[((b*64+dd)*9+o)*4096 + n]  (conv NCHW image, ch = dd*9+o)
// block: 16 n-positions; LDS tile = contiguous 288 rows x 64 (pad to 68).
// ---------------------------------------------------------------------------
__global__ __launch_bounds__(256) void fc_kernel(
    const bf16* __restrict__ qkv, const float* __restrict__ fc_w,
    const float* __restrict__ fc_b, bf16* __restrict__ fconv)
{
    const int tid = threadIdx.x;
    const int n0 = blockIdx.x * 16;
    const int b  = blockIdx.y;

    __shared__ bf16 tile[288 * 68];
    __shared__ float wf[9 * 18];
    __shared__ float wb[9];
    if (tid < 162) wf[tid] = fc_w[tid];
    if (tid < 9)   wb[tid] = fc_b[tid];

    const bf16* src = qkv + ((size_t)b * 73728 + (size_t)n0 * 18) * 64;
    for (int v = tid; v < 288 * 16; v += 256) {   // 4-elem (8B) units
        const int row = v >> 4, seg = v & 15;
        *(bfx4*)(void*)(tile + row * 68 + seg * 4) =
            *(const bfx4*)(const void*)(src + row * 64 + seg * 4);
    }
    __syncthreads();

#pragma unroll
    for (int it = 0; it < 4; ++it) {
        const int nl = tid & 15;
        const int dd = (tid >> 4) + it * 16;
        float xv[18];
#pragma unroll
        for (int i = 0; i < 18; ++i) xv[i] = bf2f(tile[(nl * 18 + i) * 68 + dd]);
#pragma unroll
        for (int o = 0; o < 9; ++o) {
            float s = wb[o];
#pragma unroll
            for (int i = 0; i < 18; ++i) s += wf[o * 18 + i] * xv[i];
            fconv[(((size_t)(b * 64 + dd)) * 9 + o) * 4096 + n0 + nl] = f2bf(s);
        }
    }
}

// ---------------------------------------------------------------------------
// grouped 3x3 conv: out[b,oc,h,w] = dep_b[oc]
//    + sum_{j,dy,dx} img[b, (oc/6)*9+j, h+dy-1, w+dx-1] * dep_w[oc,j,dy,dx]
// block = (half-image, dd, b); 9 channels of 34x66 halo-padded LDS tile.
// output fp32 in [b][oc][n] layout (coalesced float4 stores).
// ---------------------------------------------------------------------------
__global__ __launch_bounds__(256) void conv_kernel(
    const bf16* __restrict__ fconv, const float* __restrict__ dep_w,
    const float* __restrict__ dep_b, float* __restrict__ cvo)
{
    const int tid  = threadIdx.x;
    const int half = blockIdx.x, dd = blockIdx.y, b = blockIdx.z;
    const int h0 = half * 32;

    __shared__ bf16 img[9 * 34 * 66];   // 40392 B
    __shared__ float w[486];
    __shared__ float bb6[6];
    for (int v = tid; v < 486; v += 256) w[v] = dep_w[(size_t)dd * 486 + v];
    if (tid < 6) bb6[tid] = dep_b[dd * 6 + tid];

    const bf16* src = fconv + ((size_t)(b * 64 + dd)) * 9 * 4096;
    const bf16 zero = f2bf(0.f);
    for (int v = tid; v < 9 * 34 * 66; v += 256) {
        const int j  = v / 2244;
        const int rm = v % 2244;
        const int rl = rm / 66, cc = rm % 66;
        const int h = h0 - 1 + rl, wg = cc - 1;
        bf16 val = zero;
        if (h >= 0 && h < 64 && wg >= 0 && wg < 64)
            val = src[(size_t)j * 4096 + h * 64 + wg];
        img[v] = val;
    }
    __syncthreads();

    for (int ocl = 0; ocl < 6; ++ocl) {
        const float* wp = w + ocl * 81;
        for (int s = tid; s < 512; s += 256) {
            const int hl = s >> 4;          // 0..31
            const int w0 = (s & 15) * 4;    // 0..60
            float a0 = bb6[ocl], a1 = a0, a2 = a0, a3 = a0;
#pragma unroll
            for (int j = 0; j < 9; ++j) {
#pragma unroll
                for (int dy = 0; dy < 3; ++dy) {
                    const bf16* rp = img + j * 2244 + (hl + dy) * 66 + w0;
                    const float x0 = bf2f(rp[0]), x1 = bf2f(rp[1]), x2 = bf2f(rp[2]),
                                x3 = bf2f(rp[3]), x4 = bf2f(rp[4]), x5 = bf2f(rp[5]);
                    const float* wr = wp + j * 9 + dy * 3;
                    const float k0 = wr[0], k1 = wr[1], k2 = wr[2];
                    a0 += k0 * x0 + k1 * x1 + k2 * x2;
                    a1 += k0 * x1 + k1 * x2 + k2 * x3;
                    a2 += k0 * x2 + k1 * x3 + k2 * x4;
                    a3 += k0 * x3 + k1 * x4 + k2 * x5;
                }
            }
            const size_t base =
                ((size_t)(b * 384 + dd * 6 + ocl)) * 4096 + (h0 + hl) * 64 + w0;
            *(fx4*)(void*)(cvo + base) = (fx4){a0, a1, a2, a3};
        }
    }
}

// ---------------------------------------------------------------------------
// LayerNorm over C + exact GELU; reads [b][oc][n] fp32, writes [b][n][c] bf16
// ---------------------------------------------------------------------------
__global__ __launch_bounds__(256) void ln_gelu_kernel(
    const float* __restrict__ cvo, const float* __restrict__ ln_g,
    const float* __restrict__ ln_b, bf16* __restrict__ gel)
{
    const int tid = threadIdx.x;
    const int n0 = blockIdx.x * 32;
    const int b  = blockIdx.y;

    __shared__ float tile[384 * 33];   // padded transpose tile
    __shared__ float ps[32 * 9], pq[32 * 9];
    __shared__ float mu_s[32], inv_s[32];

    const float* src = cvo + (size_t)b * 384 * 4096;
    for (int v = tid; v < 384 * 32; v += 256) {
        const int oc = v >> 5, nl = v & 31;
        tile[oc * 33 + nl] = src[(size_t)oc * 4096 + n0 + nl];
    }
    __syncthreads();

    {
        const int nl = tid & 31, sl = tid >> 5;   // 8 slices of 48 channels
        float s = 0.f, q = 0.f;
        for (int oc = sl * 48; oc < sl * 48 + 48; ++oc) {
            const float xv = tile[oc * 33 + nl];
            s += xv; q += xv * xv;
        }
        ps[nl * 9 + sl] = s; pq[nl * 9 + sl] = q;
    }
    __syncthreads();
    if (tid < 32) {
        float s = 0.f, q = 0.f;
        for (int k = 0; k < 8; ++k) { s += ps[tid * 9 + k]; q += pq[tid * 9 + k]; }
        const float mu = s * (1.f / 384.f);
        const float var = q * (1.f / 384.f) - mu * mu;
        mu_s[tid] = mu; inv_s[tid] = rsqrtf(var + 1e-5f);
    }
    __syncthreads();

    for (int v = tid; v < 384 * 32; v += 256) {
        const int oc = v % 384, nl = v / 384;
        const float xv = tile[oc * 33 + nl];
        const float y = (xv - mu_s[nl]) * inv_s[nl] * ln_g[oc] + ln_b[oc];
        const float g = 0.5f * y * (1.f + erff(y * 0.70710678118f));
        gel[((size_t)b * 4096 + n0 + nl) * 384 + oc] = f2bf(g);
    }
}

// ---------------------------------------------------------------------------
extern "C" void kernel_launch(void* const* d_in, const int* in_sizes, int n_in,
                              void* d_out, int out_size, void* d_ws, size_t ws_size,
                              hipStream_t stream)
{
    // Reference dtypes are float32 -> all tensor inputs are const float*.
    const float* x      = (const float*)d_in[0];
    const float* q_w    = (const float*)d_in[1];
    const float* q_b    = (const float*)d_in[2];
    const float* kv_w   = (const float*)d_in[3];
    const float* kv_b   = (const float*)d_in[4];
    const float* fc_w   = (const float*)d_in[5];
    const float* fc_b   = (const float*)d_in[6];
    const float* dep_w  = (const float*)d_in[7];
    const float* dep_b  = (const float*)d_in[8];
    const float* ln_g   = (const float*)d_in[9];
    const float* ln_b   = (const float*)d_in[10];
    const float* proj_w = (const float*)d_in[11];
    const float* proj_b = (const float*)d_in[12];
    // d_in[13] = H, d_in[14] = W (int, fixed 64/64 — hard-coded)

    char* ws = (char*)d_ws;
    bf16*  qkv   = (bf16*)ws;                                        // 75,497,472 B
    bf16*  fconv = (bf16*)(ws + 75497472);                           // 37,748,736 B
    float* cvo   = (float*)(ws + 75497472 + 37748736);               // 50,331,648 B
    bf16*  gel   = (bf16*)(ws + 75497472 + 37748736 + 50331648);     // 25,165,824 B

    // 1) qkv = X @ [q_w;kv_w]^T + bias (fp32 in, bf16 MFMA), scatter [b][g][m][dd]
    gemm_tile<0><<<dim3(9, 256), 256, 0, stream>>>(x, q_w, kv_w, q_b, kv_b, qkv);
    // 2) fc 1x1 conv over the 18 scrambled channels -> conv image layout
    fc_kernel<<<dim3(256, 8), 256, 0, stream>>>(qkv, fc_w, fc_b, fconv);
    // 3) grouped 3x3 conv -> fp32 [b][oc][n]
    conv_kernel<<<dim3(2, 64, 8), 256, 0, stream>>>(fconv, dep_w, dep_b, cvo);
    // 4) LayerNorm + exact GELU -> bf16 [b][n][c]
    ln_gelu_kernel<<<dim3(128, 8), 256, 0, stream>>>(cvo, ln_g, ln_b, gel);
    // 5) out = gelu @ proj_w^T + proj_b  (fp32 output)
    gemm_tile<1><<<dim3(3, 256), 256, 0, stream>>>(gel, proj_w, nullptr, proj_b,
                                                   nullptr, d_out);
}

// Round 4
// 341.328 us; speedup vs baseline: 1.6875x; 1.6875x over previous
//
#include <hip/hip_runtime.h>
#include <hip/hip_bf16.h>

typedef __hip_bfloat16 bf16;
typedef __attribute__((ext_vector_type(8))) short bfx8;
typedef __attribute__((ext_vector_type(4))) short bfx4;
typedef __attribute__((ext_vector_type(4))) float fx4;
typedef __attribute__((ext_vector_type(4))) int ix4;
typedef __attribute__((ext_vector_type(2))) int ix2;

#define KD 384
#define CH 384

__device__ __forceinline__ float bf2f(bf16 v) { return __bfloat162float(v); }
__device__ __forceinline__ bf16 f2bf(float v) { return __float2bfloat16(v); }
__device__ __forceinline__ int pk2(float x, float y) {
    return (int)(((unsigned)__bfloat16_as_ushort(__float2bfloat16(y)) << 16) |
                 (unsigned)__bfloat16_as_ushort(__float2bfloat16(x)));
}

typedef const __attribute__((address_space(1))) void gvoid;
typedef __attribute__((address_space(3))) void lvoid;
__device__ __forceinline__ void gload16(const void* g, void* l) {
    __builtin_amdgcn_global_load_lds((gvoid*)g, (lvoid*)l, 16, 0, 0);
}

// ---------------------------------------------------------------------------
// cast: fp32 -> bf16 for [x | q_w | kv_w | proj_w] into one contiguous span.
// 12864 blocks x 256 threads, one float4 per thread.
// ---------------------------------------------------------------------------
__global__ __launch_bounds__(256) void cast_kernel(
    const float* __restrict__ x, const float* __restrict__ qw,
    const float* __restrict__ kvw, const float* __restrict__ pw,
    bf16* __restrict__ dst)
{
    const int i = blockIdx.x * 256 + threadIdx.x;   // float4 index
    const float* s; int off;
    if (i < 3145728)      { s = x;   off = i; }
    else if (i < 3182592) { s = qw;  off = i - 3145728; }
    else if (i < 3256320) { s = kvw; off = i - 3182592; }
    else                  { s = pw;  off = i - 3256320; }
    const fx4 v = *(const fx4*)(s + (size_t)off * 4);
    const ix2 p = (ix2){pk2(v[0], v[1]), pk2(v[2], v[3])};
    *(ix2*)(void*)(dst + (size_t)i * 4) = p;
}

// ---------------------------------------------------------------------------
// GEMM (all-bf16, m97 structure): C[r,oc] = sum_k A[r,k]*B[oc,k] + bias[oc]
// MODE 0: B = [q_w;kv_w] bf16; scatter bf16 -> qkv natural [b][g][m][dd]
// MODE 1: B = proj_w bf16; fp32 store [r][oc] to d_out
// 128x128 tile, 4 waves, 4x4 MFMA 16x16x32, global_load_lds width=16.
// ---------------------------------------------------------------------------
template <int MODE>
__global__ __launch_bounds__(256) void gemm_tile(
    const bf16* __restrict__ A, const bf16* __restrict__ B0,
    const bf16* __restrict__ B1, const float* __restrict__ bias0,
    const float* __restrict__ bias1, void* __restrict__ outv)
{
    const int tid  = threadIdx.x;
    const int wave = tid >> 6, lane = tid & 63;
    const int n0 = blockIdx.x * 128;
    const int m0 = blockIdx.y * 128;

    const bf16* Bsrc;
    const float* bsrc;
    int boff;
    if constexpr (MODE == 0) {
        if (n0 >= CH) { Bsrc = B1 + (size_t)(n0 - CH) * KD; bsrc = bias1; boff = n0 - CH; }
        else          { Bsrc = B0 + (size_t)n0 * KD;        bsrc = bias0; boff = n0; }
    } else {
        Bsrc = B0 + (size_t)n0 * KD; bsrc = bias0; boff = n0;
    }

    const int wm = (wave & 1) * 64, wn = (wave >> 1) * 64;
    const int r16 = lane & 15, quad = lane >> 4;
    const int sr = lane >> 2, sseg = lane & 3;

    __shared__ bf16 As[128 * 32];
    __shared__ bf16 Bs[128 * 32];

    fx4 acc[4][4];
#pragma unroll
    for (int i = 0; i < 4; ++i)
#pragma unroll
        for (int j = 0; j < 4; ++j) acc[i][j] = (fx4){0.f, 0.f, 0.f, 0.f};

    for (int kt = 0; kt < KD; kt += 32) {
        __syncthreads();
#pragma unroll
        for (int ii = 0; ii < 2; ++ii) {
            const int c = ii * 4 + wave;
            const int r = c * 16 + sr;
            gload16(A + (size_t)(m0 + r) * KD + kt + sseg * 8, (char*)As + c * 1024);
            gload16(Bsrc + (size_t)r * KD + kt + sseg * 8, (char*)Bs + c * 1024);
        }
        __syncthreads();   // vmcnt(0) drain: async loads landed

        bfx8 af[4], bfr[4];
#pragma unroll
        for (int t = 0; t < 4; ++t) {
            af[t]  = *(const bfx8*)(const void*)(As + (wm + t * 16 + r16) * 32 + quad * 8);
            bfr[t] = *(const bfx8*)(const void*)(Bs + (wn + t * 16 + r16) * 32 + quad * 8);
        }
#pragma unroll
        for (int i = 0; i < 4; ++i)
#pragma unroll
            for (int j = 0; j < 4; ++j)
                acc[i][j] = __builtin_amdgcn_mfma_f32_16x16x32_bf16(
                    af[i], bfr[j], acc[i][j], 0, 0, 0);
    }

#pragma unroll
    for (int j = 0; j < 4; ++j) {
        const int oc_loc = wn + j * 16 + r16;
        const int oc = n0 + oc_loc;
        const float bv = bsrc[boff + oc_loc];
#pragma unroll
        for (int i = 0; i < 4; ++i) {
#pragma unroll
            for (int v = 0; v < 4; ++v) {
                const int r = m0 + wm + i * 16 + quad * 4 + v;
                const float val = acc[i][j][v] + bv;
                if constexpr (MODE == 0) {
                    const int bb = r >> 12, m = r & 4095;
                    const int g = oc >> 6, dd = oc & 63;
                    ((bf16*)outv)[(((size_t)bb * 18 + g) * 4096 + m) * 64 + dd] = f2bf(val);
                } else {
                    ((float*)outv)[(size_t)r * CH + oc] = val;
                }
            }
        }
    }
}

// ---------------------------------------------------------------------------
// fc: f_conv[b,o,n,dd] = fc_b[o] + sum_i fc_w[o,i]*qkv[b][n*18+i][dd]
// -> fconv[((b*64+dd)*9+o)*4096 + n].  Packed b32 dd-pair LDS reads;
// fc weights via block-uniform global loads (s_load broadcast).
// ---------------------------------------------------------------------------
__global__ __launch_bounds__(256) void fc_kernel(
    const bf16* __restrict__ qkv, const float* __restrict__ fc_w,
    const float* __restrict__ fc_b, bf16* __restrict__ fconv)
{
    const int tid = threadIdx.x;
    const int n0 = blockIdx.x * 16;
    const int b  = blockIdx.y;

    __shared__ bf16 tile[288 * 68];

    const bf16* src = qkv + ((size_t)b * 73728 + (size_t)n0 * 18) * 64;
    for (int v = tid; v < 288 * 16; v += 256) {
        const int row = v >> 4, seg = v & 15;
        *(bfx4*)(void*)(tile + row * 68 + seg * 4) =
            *(const bfx4*)(const void*)(src + row * 64 + seg * 4);
    }
    __syncthreads();

    const int nl = tid & 15;
#pragma unroll
    for (int it = 0; it < 2; ++it) {
        const int p = (tid >> 4) + it * 16;     // dd pair 0..31
        float xa[18], xb_[18];
#pragma unroll
        for (int i = 0; i < 18; ++i) {
            const int u = *(const int*)(const void*)(tile + (nl * 18 + i) * 68 + 2 * p);
            xa[i]  = __uint_as_float((unsigned)u << 16);
            xb_[i] = __uint_as_float((unsigned)u & 0xffff0000u);
        }
#pragma unroll
        for (int o = 0; o < 9; ++o) {
            float s0 = fc_b[o], s1 = s0;
#pragma unroll
            for (int i = 0; i < 18; ++i) {
                const float wv = fc_w[o * 18 + i];
                s0 += wv * xa[i]; s1 += wv * xb_[i];
            }
            const size_t base0 = (((size_t)(b * 64 + 2 * p)) * 9 + o) * 4096 + n0 + nl;
            fconv[base0] = f2bf(s0);
            fconv[base0 + 9 * 4096] = f2bf(s1);
        }
    }
}

// ---------------------------------------------------------------------------
// grouped 3x3 conv v2: fp32 halo tile in LDS (ds_read_b128 rows), all 6
// output channels per image pass, weights via uniform global loads.
// block = (quarter q, dd, b); 16 output rows; 256 threads = 1 strip of 4 px.
// ---------------------------------------------------------------------------
__global__ __launch_bounds__(256) void conv_kernel(
    const bf16* __restrict__ fconv, const float* __restrict__ dep_w,
    const float* __restrict__ dep_b, float* __restrict__ cvo)
{
    const int tid = threadIdx.x;
    const int q = blockIdx.x, dd = blockIdx.y, b = blockIdx.z;
    const int h0 = q * 16;

    __shared__ float img[9 * 18 * 68];   // 44064 B; row: [w-1, w0..63, w64, pad2]

    const bf16* src = fconv + ((size_t)(b * 64 + dd)) * 9 * 4096;
    for (int v = tid; v < 9 * 18 * 66; v += 256) {
        const int j  = v / 1188;
        const int rm = v - j * 1188;
        const int r  = rm / 66, cc = rm - (rm / 66) * 66;
        const int h = h0 - 1 + r, wg = cc - 1;
        float val = 0.f;
        if (h >= 0 && h < 64 && wg >= 0 && wg < 64)
            val = bf2f(src[(size_t)j * 4096 + h * 64 + wg]);
        img[(j * 18 + r) * 68 + cc] = val;
    }
    __syncthreads();

    const int r_out = tid >> 4;          // 0..15
    const int w0 = (tid & 15) * 4;       // 0..60

    const float* bp = dep_b + dd * 6;
    float acc[6][4];
#pragma unroll
    for (int oc = 0; oc < 6; ++oc) {
        const float bv = bp[oc];
#pragma unroll
        for (int k = 0; k < 4; ++k) acc[oc][k] = bv;
    }

    const float* wbase = dep_w + (size_t)dd * 486;
    for (int j = 0; j < 9; ++j) {
        float wj[6][9];
#pragma unroll
        for (int oc = 0; oc < 6; ++oc)
#pragma unroll
            for (int t = 0; t < 9; ++t) wj[oc][t] = wbase[oc * 81 + j * 9 + t];
#pragma unroll
        for (int dy = 0; dy < 3; ++dy) {
            const float* rp = img + (j * 18 + r_out + dy) * 68 + w0;
            const fx4 x03 = *(const fx4*)rp;          // ds_read_b128 (16B aligned)
            const float x4 = rp[4], x5 = rp[5];       // ds_read_b64
#pragma unroll
            for (int oc = 0; oc < 6; ++oc) {
                const float k0 = wj[oc][dy * 3], k1 = wj[oc][dy * 3 + 1], k2 = wj[oc][dy * 3 + 2];
                acc[oc][0] += k0 * x03[0] + k1 * x03[1] + k2 * x03[2];
                acc[oc][1] += k0 * x03[1] + k1 * x03[2] + k2 * x03[3];
                acc[oc][2] += k0 * x03[2] + k1 * x03[3] + k2 * x4;
                acc[oc][3] += k0 * x03[3] + k1 * x4 + k2 * x5;
            }
        }
    }

#pragma unroll
    for (int oc = 0; oc < 6; ++oc) {
        const size_t base =
            ((size_t)(b * 384 + dd * 6 + oc)) * 4096 + (h0 + r_out) * 64 + w0;
        *(fx4*)(void*)(cvo + base) = (fx4){acc[oc][0], acc[oc][1], acc[oc][2], acc[oc][3]};
    }
}

// ---------------------------------------------------------------------------
// LayerNorm over C + exact GELU; reads [b][oc][n] fp32, writes [b][n][c] bf16
// ---------------------------------------------------------------------------
__global__ __launch_bounds__(256) void ln_gelu_kernel(
    const float* __restrict__ cvo, const float* __restrict__ ln_g,
    const float* __restrict__ ln_b, bf16* __restrict__ gel)
{
    const int tid = threadIdx.x;
    const int n0 = blockIdx.x * 32;
    const int b  = blockIdx.y;

    __shared__ float tile[384 * 33];
    __shared__ float ps[32 * 9], pq[32 * 9];
    __shared__ float mu_s[32], inv_s[32];

    const float* src = cvo + (size_t)b * 384 * 4096;
    for (int v = tid; v < 384 * 32; v += 256) {
        const int oc = v >> 5, nl = v & 31;
        tile[oc * 33 + nl] = src[(size_t)oc * 4096 + n0 + nl];
    }
    __syncthreads();

    {
        const int nl = tid & 31, sl = tid >> 5;
        float s = 0.f, q = 0.f;
        for (int oc = sl * 48; oc < sl * 48 + 48; ++oc) {
            const float xv = tile[oc * 33 + nl];
            s += xv; q += xv * xv;
        }
        ps[nl * 9 + sl] = s; pq[nl * 9 + sl] = q;
    }
    __syncthreads();
    if (tid < 32) {
        float s = 0.f, q = 0.f;
        for (int k = 0; k < 8; ++k) { s += ps[tid * 9 + k]; q += pq[tid * 9 + k]; }
        const float mu = s * (1.f / 384.f);
        const float var = q * (1.f / 384.f) - mu * mu;
        mu_s[tid] = mu; inv_s[tid] = rsqrtf(var + 1e-5f);
    }
    __syncthreads();

    for (int v = tid; v < 384 * 32; v += 256) {
        const int oc = v % 384, nl = v / 384;
        const float xv = tile[oc * 33 + nl];
        const float y = (xv - mu_s[nl]) * inv_s[nl] * ln_g[oc] + ln_b[oc];
        const float g = 0.5f * y * (1.f + erff(y * 0.70710678118f));
        gel[((size_t)b * 4096 + n0 + nl) * 384 + oc] = f2bf(g);
    }
}

// ---------------------------------------------------------------------------
extern "C" void kernel_launch(void* const* d_in, const int* in_sizes, int n_in,
                              void* d_out, int out_size, void* d_ws, size_t ws_size,
                              hipStream_t stream)
{
    const float* x      = (const float*)d_in[0];
    const float* q_b    = (const float*)d_in[2];
    const float* q_w    = (const float*)d_in[1];
    const float* kv_w   = (const float*)d_in[3];
    const float* kv_b   = (const float*)d_in[4];
    const float* fc_w   = (const float*)d_in[5];
    const float* fc_b   = (const float*)d_in[6];
    const float* dep_w  = (const float*)d_in[7];
    const float* dep_b  = (const float*)d_in[8];
    const float* ln_g   = (const float*)d_in[9];
    const float* ln_b   = (const float*)d_in[10];
    const float* proj_w = (const float*)d_in[11];
    const float* proj_b = (const float*)d_in[12];

    // workspace layout (overlays exploit liveness; total 139,591,680 B):
    //   [0,26345472)            bf16 cast span: xb | qwb | kvwb | projwb
    //   [26345472,101842944)    qkv bf16      (dead after fc)  <- cvo overlays
    //   [101842944,139591680)   fconv bf16    (dead after conv) <- gel overlays
    char* ws = (char*)d_ws;
    bf16*  castspan = (bf16*)ws;
    bf16*  xb     = castspan;                       // 12,582,912 elems
    bf16*  qwb    = castspan + 12582912;            //    147,456
    bf16*  kvwb   = castspan + 12730368;            //    294,912
    bf16*  projwb = castspan + 13025280;            //    147,456
    bf16*  qkv    = (bf16*)(ws + 26345472);
    bf16*  fconv  = (bf16*)(ws + 101842944);
    float* cvo    = (float*)(ws + 26345472);        // overlays qkv
    bf16*  gel    = (bf16*)(ws + 101842944);        // overlays fconv

    // 0) fp32 -> bf16 cast of x and the three GEMM weight matrices
    cast_kernel<<<dim3(12864), 256, 0, stream>>>(x, q_w, kv_w, proj_w, castspan);
    // 1) qkv = X @ [q_w;kv_w]^T + bias, scatter [b][g][m][dd]
    gemm_tile<0><<<dim3(9, 256), 256, 0, stream>>>(xb, qwb, kvwb, q_b, kv_b, qkv);
    // 2) fc 1x1 conv -> conv image layout
    fc_kernel<<<dim3(256, 8), 256, 0, stream>>>(qkv, fc_w, fc_b, fconv);
    // 3) grouped 3x3 conv -> fp32 [b][oc][n]  (writes over dead qkv)
    conv_kernel<<<dim3(4, 64, 8), 256, 0, stream>>>(fconv, dep_w, dep_b, cvo);
    // 4) LayerNorm + exact GELU -> bf16 [b][n][c]  (writes over dead fconv)
    ln_gelu_kernel<<<dim3(128, 8), 256, 0, stream>>>(cvo, ln_g, ln_b, gel);
    // 5) out = gelu @ proj_w^T + proj_b  (fp32 output)
    gemm_tile<1><<<dim3(3, 256), 256, 0, stream>>>(gel, projwb, nullptr, proj_b,
                                                   nullptr, d_out);
}

// Round 5
// 283.879 us; speedup vs baseline: 2.0290x; 1.2024x over previous
//
#include <hip/hip_runtime.h>
#include <hip/hip_bf16.h>

typedef __hip_bfloat16 bf16;
typedef __attribute__((ext_vector_type(8))) short bfx8;
typedef __attribute__((ext_vector_type(4))) short bfx4;
typedef __attribute__((ext_vector_type(4))) float fx4;
typedef __attribute__((ext_vector_type(4))) int ix4;
typedef __attribute__((ext_vector_type(2))) int ix2;

#define KD 384
#define CH 384

__device__ __forceinline__ float bf2f(bf16 v) { return __bfloat162float(v); }
__device__ __forceinline__ bf16 f2bf(float v) { return __float2bfloat16(v); }
__device__ __forceinline__ int pk2(float x, float y) {
    return (int)(((unsigned)__bfloat16_as_ushort(__float2bfloat16(y)) << 16) |
                 (unsigned)__bfloat16_as_ushort(__float2bfloat16(x)));
}
__device__ __forceinline__ float lo16(int u) { return __uint_as_float((unsigned)u << 16); }
__device__ __forceinline__ float hi16(int u) { return __uint_as_float((unsigned)u & 0xffff0000u); }

typedef const __attribute__((address_space(1))) void gvoid;
typedef __attribute__((address_space(3))) void lvoid;
__device__ __forceinline__ void gload16(const void* g, void* l) {
    __builtin_amdgcn_global_load_lds((gvoid*)g, (lvoid*)l, 16, 0, 0);
}

// ---------------------------------------------------------------------------
// cast: fp32 -> bf16 for [x | q_w | kv_w | proj_w] into one contiguous span.
// ---------------------------------------------------------------------------
__global__ __launch_bounds__(256) void cast_kernel(
    const float* __restrict__ x, const float* __restrict__ qw,
    const float* __restrict__ kvw, const float* __restrict__ pw,
    bf16* __restrict__ dst)
{
    const int i = blockIdx.x * 256 + threadIdx.x;   // float4 index
    const float* s; int off;
    if (i < 3145728)      { s = x;   off = i; }
    else if (i < 3182592) { s = qw;  off = i - 3145728; }
    else if (i < 3256320) { s = kvw; off = i - 3182592; }
    else                  { s = pw;  off = i - 3256320; }
    const fx4 v = *(const fx4*)(s + (size_t)off * 4);
    const ix2 p = (ix2){pk2(v[0], v[1]), pk2(v[2], v[3])};
    *(ix2*)(void*)(dst + (size_t)i * 4) = p;
}

// ---------------------------------------------------------------------------
// GEMM (bf16, m97 structure): C[r,oc] = sum_k A[r,k]*B[oc,k] + bias[oc]
// MODE 0: B = [q_w;kv_w]; epilogue LDS-transpose -> qkv2[b][dd][t] bf16
//         (t = g*4096 + m, oc = g*64+dd) with coalesced 256B store runs.
// MODE 1: B = proj_w; fp32 store [r][oc] to d_out.
// 128x128 tile, 4 waves, 4x4 MFMA 16x16x32, global_load_lds width=16.
// ---------------------------------------------------------------------------
template <int MODE>
__global__ __launch_bounds__(256) void gemm_tile(
    const bf16* __restrict__ A, const bf16* __restrict__ B0,
    const bf16* __restrict__ B1, const float* __restrict__ bias0,
    const float* __restrict__ bias1, void* __restrict__ outv)
{
    const int tid  = threadIdx.x;
    const int wave = tid >> 6, lane = tid & 63;
    const int n0 = blockIdx.x * 128;
    const int m0 = blockIdx.y * 128;

    const bf16* Bsrc;
    const float* bsrc;
    int boff;
    if constexpr (MODE == 0) {
        if (n0 >= CH) { Bsrc = B1 + (size_t)(n0 - CH) * KD; bsrc = bias1; boff = n0 - CH; }
        else          { Bsrc = B0 + (size_t)n0 * KD;        bsrc = bias0; boff = n0; }
    } else {
        Bsrc = B0 + (size_t)n0 * KD; bsrc = bias0; boff = n0;
    }

    const int wm = (wave & 1) * 64, wn = (wave >> 1) * 64;
    const int r16 = lane & 15, quad = lane >> 4;
    const int sr = lane >> 2, sseg = lane & 3;

    __shared__ bf16 As[128 * 32];
    __shared__ bf16 Bs[128 * 32];

    fx4 acc[4][4];
#pragma unroll
    for (int i = 0; i < 4; ++i)
#pragma unroll
        for (int j = 0; j < 4; ++j) acc[i][j] = (fx4){0.f, 0.f, 0.f, 0.f};

    for (int kt = 0; kt < KD; kt += 32) {
        __syncthreads();
#pragma unroll
        for (int ii = 0; ii < 2; ++ii) {
            const int c = ii * 4 + wave;
            const int r = c * 16 + sr;
            gload16(A + (size_t)(m0 + r) * KD + kt + sseg * 8, (char*)As + c * 1024);
            gload16(Bsrc + (size_t)r * KD + kt + sseg * 8, (char*)Bs + c * 1024);
        }
        __syncthreads();   // vmcnt(0) drain: async loads landed

        bfx8 af[4], bfr[4];
#pragma unroll
        for (int t = 0; t < 4; ++t) {
            af[t]  = *(const bfx8*)(const void*)(As + (wm + t * 16 + r16) * 32 + quad * 8);
            bfr[t] = *(const bfx8*)(const void*)(Bs + (wn + t * 16 + r16) * 32 + quad * 8);
        }
#pragma unroll
        for (int i = 0; i < 4; ++i)
#pragma unroll
            for (int j = 0; j < 4; ++j)
                acc[i][j] = __builtin_amdgcn_mfma_f32_16x16x32_bf16(
                    af[i], bfr[j], acc[i][j], 0, 0, 0);
    }

    if constexpr (MODE == 0) {
        // epilogue: bias + transpose through LDS, store [b][dd][g][m] bf16
        __shared__ bf16 tr[64 * 136];   // [ocl 0..63][m 0..127 + pad8]
        const int bb = m0 >> 12, mbase = m0 & 4095;
#pragma unroll
        for (int half = 0; half < 2; ++half) {
            __syncthreads();
            if ((wave >> 1) == half) {
#pragma unroll
                for (int j = 0; j < 4; ++j) {
                    const int ocl = j * 16 + r16;                 // 0..63 in half
                    const float bv = bsrc[boff + wn + j * 16 + r16];
#pragma unroll
                    for (int i = 0; i < 4; ++i) {
                        const int m_loc = wm + i * 16 + quad * 4;
                        const ix2 pr = (ix2){
                            pk2(acc[i][j][0] + bv, acc[i][j][1] + bv),
                            pk2(acc[i][j][2] + bv, acc[i][j][3] + bv)};
                        *(ix2*)(void*)(tr + ocl * 136 + m_loc) = pr;
                    }
                }
            }
            __syncthreads();
            bf16* outp = (bf16*)outv;
            for (int u = tid; u < 1024; u += 256) {
                const int ocl = u >> 4, seg = u & 15;
                const int oc = n0 + half * 64 + ocl;
                const int g = oc >> 6, dd = oc & 63;
                const ix4 val = *(const ix4*)(const void*)(tr + ocl * 136 + seg * 8);
                const size_t dst = (((size_t)(bb * 64 + dd)) * 18 + g) * 4096 + mbase + seg * 8;
                *(ix4*)(void*)(outp + dst) = val;
            }
        }
    } else {
#pragma unroll
        for (int j = 0; j < 4; ++j) {
            const int oc = n0 + wn + j * 16 + r16;
            const float bv = bsrc[boff + wn + j * 16 + r16];
#pragma unroll
            for (int i = 0; i < 4; ++i) {
#pragma unroll
                for (int v = 0; v < 4; ++v) {
                    const int r = m0 + wm + i * 16 + quad * 4 + v;
                    ((float*)outv)[(size_t)r * CH + oc] = acc[i][j][v] + bv;
                }
            }
        }
    }
}

// ---------------------------------------------------------------------------
// fused fc + grouped 3x3 conv.
// qkv2[b][dd][t] (t = n*18+i gives the 18 fc inputs of pixel n CONTIGUOUS).
// Per block (q,dd,b): compute fc into a bf16 halo tile img[9][18][68] in LDS
// (halo pixels = 0: conv zero-pads AFTER fc), then 3x3 conv, 6 out channels,
// bf16 output cvo[b][oc384][n].
// fc/dep weights+biases via block-uniform global loads (scalar pipe).
// ---------------------------------------------------------------------------
__global__ __launch_bounds__(256) void fcconv_kernel(
    const bf16* __restrict__ qkv2, const float* __restrict__ fc_w,
    const float* __restrict__ fc_b, const float* __restrict__ dep_w,
    const float* __restrict__ dep_b, bf16* __restrict__ cvo)
{
    const int tid = threadIdx.x;
    const int q = blockIdx.x, dd = blockIdx.y, b = blockIdx.z;
    const int h0 = q * 16;

    __shared__ bf16 img[9 * 18 * 68];   // 22032 B -> ~7 blocks/CU

    const bf16* qb = qkv2 + ((size_t)(b * 64 + dd)) * 73728;

    // ---- fc phase: 18 rows x 66 cols (halo) ----
    for (int p = tid; p < 18 * 66; p += 256) {
        const int r = p / 66, cc = p - r * 66;
        const int h = h0 - 1 + r, wg = cc - 1;
        float s[9];
        if (h >= 0 && h < 64 && wg >= 0 && wg < 64) {
            const int n = h * 64 + wg;
            const int* tp = (const int*)(const void*)(qb + (size_t)n * 18); // 4B aligned
            float xv[18];
#pragma unroll
            for (int k = 0; k < 9; ++k) {
                const int u = tp[k];
                xv[2 * k]     = lo16(u);
                xv[2 * k + 1] = hi16(u);
            }
#pragma unroll
            for (int o = 0; o < 9; ++o) {
                float t = fc_b[o];
#pragma unroll
                for (int i = 0; i < 18; ++i) t += fc_w[o * 18 + i] * xv[i];
                s[o] = t;
            }
        } else {
#pragma unroll
            for (int o = 0; o < 9; ++o) s[o] = 0.f;
        }
#pragma unroll
        for (int o = 0; o < 9; ++o) img[(o * 18 + r) * 68 + cc] = f2bf(s[o]);
    }
    __syncthreads();

    // ---- conv phase ----
    const int r_out = tid >> 4;          // 0..15
    const int w0 = (tid & 15) * 4;       // 0..60

    float acc[6][4];
#pragma unroll
    for (int oc = 0; oc < 6; ++oc) {
        const float bv = dep_b[dd * 6 + oc];
#pragma unroll
        for (int k = 0; k < 4; ++k) acc[oc][k] = bv;
    }

    const float* wbase = dep_w + (size_t)dd * 486;
    for (int j = 0; j < 9; ++j) {
        float wj[6][9];
#pragma unroll
        for (int oc = 0; oc < 6; ++oc)
#pragma unroll
            for (int t = 0; t < 9; ++t) wj[oc][t] = wbase[oc * 81 + j * 9 + t];
#pragma unroll
        for (int dy = 0; dy < 3; ++dy) {
            const bf16* rp = img + (j * 18 + r_out + dy) * 68 + w0;   // 8B aligned
            const ix2 d01 = *(const ix2*)(const void*)rp;
            const int d2 = *(const int*)(const void*)(rp + 4);
            const float x0 = lo16(d01[0]), x1 = hi16(d01[0]);
            const float x2 = lo16(d01[1]), x3 = hi16(d01[1]);
            const float x4 = lo16(d2),     x5 = hi16(d2);
#pragma unroll
            for (int oc = 0; oc < 6; ++oc) {
                const float k0 = wj[oc][dy * 3], k1 = wj[oc][dy * 3 + 1], k2 = wj[oc][dy * 3 + 2];
                acc[oc][0] += k0 * x0 + k1 * x1 + k2 * x2;
                acc[oc][1] += k0 * x1 + k1 * x2 + k2 * x3;
                acc[oc][2] += k0 * x2 + k1 * x3 + k2 * x4;
                acc[oc][3] += k0 * x3 + k1 * x4 + k2 * x5;
            }
        }
    }

#pragma unroll
    for (int oc = 0; oc < 6; ++oc) {
        const size_t base =
            ((size_t)(b * 384 + dd * 6 + oc)) * 4096 + (h0 + r_out) * 64 + w0;
        const ix2 pr = (ix2){pk2(acc[oc][0], acc[oc][1]), pk2(acc[oc][2], acc[oc][3])};
        *(ix2*)(void*)(cvo + base) = pr;
    }
}

// ---------------------------------------------------------------------------
// LayerNorm over C + exact GELU; reads [b][oc][n] bf16, writes [b][n][c] bf16
// ---------------------------------------------------------------------------
__global__ __launch_bounds__(256) void ln_gelu_kernel(
    const bf16* __restrict__ cvo, const float* __restrict__ ln_g,
    const float* __restrict__ ln_b, bf16* __restrict__ gel)
{
    const int tid = threadIdx.x;
    const int n0 = blockIdx.x * 32;
    const int b  = blockIdx.y;

    __shared__ float tile[384 * 33];
    __shared__ float ps[32 * 9], pq[32 * 9];
    __shared__ float mu_s[32], inv_s[32];

    const bf16* src = cvo + (size_t)b * 384 * 4096;
    for (int v = tid; v < 384 * 32; v += 256) {
        const int oc = v >> 5, nl = v & 31;
        tile[oc * 33 + nl] = bf2f(src[(size_t)oc * 4096 + n0 + nl]);
    }
    __syncthreads();

    {
        const int nl = tid & 31, sl = tid >> 5;
        float s = 0.f, q = 0.f;
        for (int oc = sl * 48; oc < sl * 48 + 48; ++oc) {
            const float xv = tile[oc * 33 + nl];
            s += xv; q += xv * xv;
        }
        ps[nl * 9 + sl] = s; pq[nl * 9 + sl] = q;
    }
    __syncthreads();
    if (tid < 32) {
        float s = 0.f, q = 0.f;
        for (int k = 0; k < 8; ++k) { s += ps[tid * 9 + k]; q += pq[tid * 9 + k]; }
        const float mu = s * (1.f / 384.f);
        const float var = q * (1.f / 384.f) - mu * mu;
        mu_s[tid] = mu; inv_s[tid] = rsqrtf(var + 1e-5f);
    }
    __syncthreads();

    for (int v = tid; v < 384 * 32; v += 256) {
        const int oc = v % 384, nl = v / 384;
        const float xv = tile[oc * 33 + nl];
        const float y = (xv - mu_s[nl]) * inv_s[nl] * ln_g[oc] + ln_b[oc];
        const float g = 0.5f * y * (1.f + erff(y * 0.70710678118f));
        gel[((size_t)b * 4096 + n0 + nl) * 384 + oc] = f2bf(g);
    }
}

// ---------------------------------------------------------------------------
extern "C" void kernel_launch(void* const* d_in, const int* in_sizes, int n_in,
                              void* d_out, int out_size, void* d_ws, size_t ws_size,
                              hipStream_t stream)
{
    const float* x      = (const float*)d_in[0];
    const float* q_w    = (const float*)d_in[1];
    const float* q_b    = (const float*)d_in[2];
    const float* kv_w   = (const float*)d_in[3];
    const float* kv_b   = (const float*)d_in[4];
    const float* fc_w   = (const float*)d_in[5];
    const float* fc_b   = (const float*)d_in[6];
    const float* dep_w  = (const float*)d_in[7];
    const float* dep_b  = (const float*)d_in[8];
    const float* ln_g   = (const float*)d_in[9];
    const float* ln_b   = (const float*)d_in[10];
    const float* proj_w = (const float*)d_in[11];
    const float* proj_b = (const float*)d_in[12];

    // workspace (no overlays; total 152,174,592 B):
    char* ws = (char*)d_ws;
    bf16*  castspan = (bf16*)ws;                    // 26,345,472 B
    bf16*  xb     = castspan;
    bf16*  qwb    = castspan + 12582912;
    bf16*  kvwb   = castspan + 12730368;
    bf16*  projwb = castspan + 13025280;
    bf16*  qkv2   = (bf16*)(ws + 26345472);         // 75,497,472 B  [b][dd][t]
    bf16*  cvo    = (bf16*)(ws + 101842944);        // 25,165,824 B  [b][oc][n]
    bf16*  gel    = (bf16*)(ws + 127008768);        // 25,165,824 B  [b][n][c]

    // 0) fp32 -> bf16 cast of x and the GEMM weight matrices
    cast_kernel<<<dim3(12864), 256, 0, stream>>>(x, q_w, kv_w, proj_w, castspan);
    // 1) qkv2 = X @ [q_w;kv_w]^T + bias, transposed store [b][dd][t]
    gemm_tile<0><<<dim3(9, 256), 256, 0, stream>>>(xb, qwb, kvwb, q_b, kv_b, qkv2);
    // 2) fused fc + grouped 3x3 conv -> bf16 [b][oc][n]
    fcconv_kernel<<<dim3(4, 64, 8), 256, 0, stream>>>(qkv2, fc_w, fc_b, dep_w,
                                                      dep_b, cvo);
    // 3) LayerNorm + exact GELU -> bf16 [b][n][c]
    ln_gelu_kernel<<<dim3(128, 8), 256, 0, stream>>>(cvo, ln_g, ln_b, gel);
    // 4) out = gelu @ proj_w^T + proj_b  (fp32 output)
    gemm_tile<1><<<dim3(3, 256), 256, 0, stream>>>(gel, projwb, nullptr, proj_b,
                                                   nullptr, d_out);
}

// Round 6
// 270.055 us; speedup vs baseline: 2.1328x; 1.0512x over previous
//
#include <hip/hip_runtime.h>
#include <hip/hip_bf16.h>

typedef __hip_bfloat16 bf16;
typedef __attribute__((ext_vector_type(8))) short bfx8;
typedef __attribute__((ext_vector_type(4))) short bfx4;
typedef __attribute__((ext_vector_type(4))) float fx4;
typedef __attribute__((ext_vector_type(4))) int ix4;
typedef __attribute__((ext_vector_type(2))) int ix2;

#define KD 384
#define CH 384

__device__ __forceinline__ float bf2f(bf16 v) { return __bfloat162float(v); }
__device__ __forceinline__ bf16 f2bf(float v) { return __float2bfloat16(v); }
__device__ __forceinline__ int pk2(float x, float y) {
    return (int)(((unsigned)__bfloat16_as_ushort(__float2bfloat16(y)) << 16) |
                 (unsigned)__bfloat16_as_ushort(__float2bfloat16(x)));
}
__device__ __forceinline__ float lo16(int u) { return __uint_as_float((unsigned)u << 16); }
__device__ __forceinline__ float hi16(int u) { return __uint_as_float((unsigned)u & 0xffff0000u); }

typedef const __attribute__((address_space(1))) void gvoid;
typedef __attribute__((address_space(3))) void lvoid;
__device__ __forceinline__ void gload16(const void* g, void* l) {
    __builtin_amdgcn_global_load_lds((gvoid*)g, (lvoid*)l, 16, 0, 0);
}

// ---------------------------------------------------------------------------
// cast: fp32 -> bf16 for [x | q_w | kv_w | proj_w] into one contiguous span.
// ---------------------------------------------------------------------------
__global__ __launch_bounds__(256) void cast_kernel(
    const float* __restrict__ x, const float* __restrict__ qw,
    const float* __restrict__ kvw, const float* __restrict__ pw,
    bf16* __restrict__ dst)
{
    const int i = blockIdx.x * 256 + threadIdx.x;   // float4 index
    const float* s; int off;
    if (i < 3145728)      { s = x;   off = i; }
    else if (i < 3182592) { s = qw;  off = i - 3145728; }
    else if (i < 3256320) { s = kvw; off = i - 3182592; }
    else                  { s = pw;  off = i - 3256320; }
    const fx4 v = *(const fx4*)(s + (size_t)off * 4);
    const ix2 p = (ix2){pk2(v[0], v[1]), pk2(v[2], v[3])};
    *(ix2*)(void*)(dst + (size_t)i * 4) = p;
}

// ---------------------------------------------------------------------------
// GEMM (bf16, m97 structure): C[r,oc] = sum_k A[r,k]*B[oc,k] + bias[oc]
// MODE 0: B = [q_w;kv_w]; epilogue LDS-transpose -> qkv2[b][dd][t] bf16
// MODE 1: B = proj_w; fp32 store [r][oc] to d_out.
// 1-D grid, XCD-aware swizzle: all NT n-tiles of an m-tile map to the same
// XCD (f&7) consecutively -> A-tile fetched ~once instead of NT times.
// MODE 0 unions the epilogue transpose buffer with As/Bs (disjoint live
// ranges, barrier-separated) -> 17.4 KB LDS -> 8 blocks/CU.
// ---------------------------------------------------------------------------
template <int MODE>
__global__ __launch_bounds__(256) void gemm_tile(
    const bf16* __restrict__ A, const bf16* __restrict__ B0,
    const bf16* __restrict__ B1, const float* __restrict__ bias0,
    const float* __restrict__ bias1, void* __restrict__ outv)
{
    constexpr int NT = (MODE == 0) ? 9 : 3;
    const int tid  = threadIdx.x;
    const int wave = tid >> 6, lane = tid & 63;

    const int f = blockIdx.x;
    const int xcd = f & 7, idx = f >> 3;
    const int mi = idx / NT, nt = idx - mi * NT;
    const int m0 = (xcd + (mi << 3)) * 128;
    const int n0 = nt * 128;

    const bf16* Bsrc;
    const float* bsrc;
    int boff;
    if constexpr (MODE == 0) {
        if (n0 >= CH) { Bsrc = B1 + (size_t)(n0 - CH) * KD; bsrc = bias1; boff = n0 - CH; }
        else          { Bsrc = B0 + (size_t)n0 * KD;        bsrc = bias0; boff = n0; }
    } else {
        Bsrc = B0 + (size_t)n0 * KD; bsrc = bias0; boff = n0;
    }

    const int wm = (wave & 1) * 64, wn = (wave >> 1) * 64;
    const int r16 = lane & 15, quad = lane >> 4;
    const int sr = lane >> 2, sseg = lane & 3;

    // LDS union: K-loop uses As|Bs (16384 B); MODE0 epilogue reuses the same
    // space as tr[64*136] (17408 B). Live ranges separated by __syncthreads.
    constexpr int SMEM = (MODE == 0) ? 17408 : 16384;
    __shared__ __align__(16) char smem[SMEM];
    bf16* As = (bf16*)smem;             // 128*32
    bf16* Bs = (bf16*)(smem + 8192);    // 128*32

    fx4 acc[4][4];
#pragma unroll
    for (int i = 0; i < 4; ++i)
#pragma unroll
        for (int j = 0; j < 4; ++j) acc[i][j] = (fx4){0.f, 0.f, 0.f, 0.f};

    for (int kt = 0; kt < KD; kt += 32) {
        __syncthreads();
#pragma unroll
        for (int ii = 0; ii < 2; ++ii) {
            const int c = ii * 4 + wave;
            const int r = c * 16 + sr;
            gload16(A + (size_t)(m0 + r) * KD + kt + sseg * 8, (char*)As + c * 1024);
            gload16(Bsrc + (size_t)r * KD + kt + sseg * 8, (char*)Bs + c * 1024);
        }
        __syncthreads();   // vmcnt(0) drain: async loads landed

        bfx8 af[4], bfr[4];
#pragma unroll
        for (int t = 0; t < 4; ++t) {
            af[t]  = *(const bfx8*)(const void*)(As + (wm + t * 16 + r16) * 32 + quad * 8);
            bfr[t] = *(const bfx8*)(const void*)(Bs + (wn + t * 16 + r16) * 32 + quad * 8);
        }
#pragma unroll
        for (int i = 0; i < 4; ++i)
#pragma unroll
            for (int j = 0; j < 4; ++j)
                acc[i][j] = __builtin_amdgcn_mfma_f32_16x16x32_bf16(
                    af[i], bfr[j], acc[i][j], 0, 0, 0);
    }

    if constexpr (MODE == 0) {
        // epilogue: bias + transpose through LDS, store [b][dd][g][m] bf16
        bf16* tr = (bf16*)smem;   // 64*136 (overlays As/Bs; barrier-protected)
        const int bb = m0 >> 12, mbase = m0 & 4095;
#pragma unroll
        for (int half = 0; half < 2; ++half) {
            __syncthreads();   // prev readers (K-loop or half 0) done
            if ((wave >> 1) == half) {
#pragma unroll
                for (int j = 0; j < 4; ++j) {
                    const int ocl = j * 16 + r16;                 // 0..63 in half
                    const float bv = bsrc[boff + wn + j * 16 + r16];
#pragma unroll
                    for (int i = 0; i < 4; ++i) {
                        const int m_loc = wm + i * 16 + quad * 4;
                        const ix2 pr = (ix2){
                            pk2(acc[i][j][0] + bv, acc[i][j][1] + bv),
                            pk2(acc[i][j][2] + bv, acc[i][j][3] + bv)};
                        *(ix2*)(void*)(tr + ocl * 136 + m_loc) = pr;
                    }
                }
            }
            __syncthreads();
            bf16* outp = (bf16*)outv;
            for (int u = tid; u < 1024; u += 256) {
                const int ocl = u >> 4, seg = u & 15;
                const int oc = n0 + half * 64 + ocl;
                const int g = oc >> 6, dd = oc & 63;
                const ix4 val = *(const ix4*)(const void*)(tr + ocl * 136 + seg * 8);
                const size_t dst = (((size_t)(bb * 64 + dd)) * 18 + g) * 4096 + mbase + seg * 8;
                *(ix4*)(void*)(outp + dst) = val;
            }
        }
    } else {
#pragma unroll
        for (int j = 0; j < 4; ++j) {
            const int oc = n0 + wn + j * 16 + r16;
            const float bv = bsrc[boff + wn + j * 16 + r16];
#pragma unroll
            for (int i = 0; i < 4; ++i) {
#pragma unroll
                for (int v = 0; v < 4; ++v) {
                    const int r = m0 + wm + i * 16 + quad * 4 + v;
                    ((float*)outv)[(size_t)r * CH + oc] = acc[i][j][v] + bv;
                }
            }
        }
    }
}

// ---------------------------------------------------------------------------
// fused fc + grouped 3x3 conv.
// qkv2[b][dd][t] (t = n*18+i gives the 18 fc inputs of pixel n CONTIGUOUS).
// Per block (q,dd,b): fc into bf16 halo tile img[9][18][68], then 3x3 conv,
// 6 out channels, bf16 output cvo[b][oc384][n].
// ---------------------------------------------------------------------------
__global__ __launch_bounds__(256) void fcconv_kernel(
    const bf16* __restrict__ qkv2, const float* __restrict__ fc_w,
    const float* __restrict__ fc_b, const float* __restrict__ dep_w,
    const float* __restrict__ dep_b, bf16* __restrict__ cvo)
{
    const int tid = threadIdx.x;
    const int q = blockIdx.x, dd = blockIdx.y, b = blockIdx.z;
    const int h0 = q * 16;

    __shared__ bf16 img[9 * 18 * 68];   // 22032 B -> ~7 blocks/CU

    const bf16* qb = qkv2 + ((size_t)(b * 64 + dd)) * 73728;

    // ---- fc phase: 18 rows x 66 cols (halo) ----
    for (int p = tid; p < 18 * 66; p += 256) {
        const int r = p / 66, cc = p - r * 66;
        const int h = h0 - 1 + r, wg = cc - 1;
        float s[9];
        if (h >= 0 && h < 64 && wg >= 0 && wg < 64) {
            const int n = h * 64 + wg;
            const int* tp = (const int*)(const void*)(qb + (size_t)n * 18);
            float xv[18];
#pragma unroll
            for (int k = 0; k < 9; ++k) {
                const int u = tp[k];
                xv[2 * k]     = lo16(u);
                xv[2 * k + 1] = hi16(u);
            }
#pragma unroll
            for (int o = 0; o < 9; ++o) {
                float t = fc_b[o];
#pragma unroll
                for (int i = 0; i < 18; ++i) t += fc_w[o * 18 + i] * xv[i];
                s[o] = t;
            }
        } else {
#pragma unroll
            for (int o = 0; o < 9; ++o) s[o] = 0.f;
        }
#pragma unroll
        for (int o = 0; o < 9; ++o) img[(o * 18 + r) * 68 + cc] = f2bf(s[o]);
    }
    __syncthreads();

    // ---- conv phase ----
    const int r_out = tid >> 4;          // 0..15
    const int w0 = (tid & 15) * 4;       // 0..60

    float acc[6][4];
#pragma unroll
    for (int oc = 0; oc < 6; ++oc) {
        const float bv = dep_b[dd * 6 + oc];
#pragma unroll
        for (int k = 0; k < 4; ++k) acc[oc][k] = bv;
    }

    const float* wbase = dep_w + (size_t)dd * 486;
    for (int j = 0; j < 9; ++j) {
        float wj[6][9];
#pragma unroll
        for (int oc = 0; oc < 6; ++oc)
#pragma unroll
            for (int t = 0; t < 9; ++t) wj[oc][t] = wbase[oc * 81 + j * 9 + t];
#pragma unroll
        for (int dy = 0; dy < 3; ++dy) {
            const bf16* rp = img + (j * 18 + r_out + dy) * 68 + w0;
            const ix2 d01 = *(const ix2*)(const void*)rp;
            const int d2 = *(const int*)(const void*)(rp + 4);
            const float x0 = lo16(d01[0]), x1 = hi16(d01[0]);
            const float x2 = lo16(d01[1]), x3 = hi16(d01[1]);
            const float x4 = lo16(d2),     x5 = hi16(d2);
#pragma unroll
            for (int oc = 0; oc < 6; ++oc) {
                const float k0 = wj[oc][dy * 3], k1 = wj[oc][dy * 3 + 1], k2 = wj[oc][dy * 3 + 2];
                acc[oc][0] += k0 * x0 + k1 * x1 + k2 * x2;
                acc[oc][1] += k0 * x1 + k1 * x2 + k2 * x3;
                acc[oc][2] += k0 * x2 + k1 * x3 + k2 * x4;
                acc[oc][3] += k0 * x3 + k1 * x4 + k2 * x5;
            }
        }
    }

#pragma unroll
    for (int oc = 0; oc < 6; ++oc) {
        const size_t base =
            ((size_t)(b * 384 + dd * 6 + oc)) * 4096 + (h0 + r_out) * 64 + w0;
        const ix2 pr = (ix2){pk2(acc[oc][0], acc[oc][1]), pk2(acc[oc][2], acc[oc][3])};
        *(ix2*)(void*)(cvo + base) = pr;
    }
}

// ---------------------------------------------------------------------------
// LayerNorm over C + exact GELU; reads [b][oc][n] bf16, writes [b][n][c] bf16
// ---------------------------------------------------------------------------
__global__ __launch_bounds__(256) void ln_gelu_kernel(
    const bf16* __restrict__ cvo, const float* __restrict__ ln_g,
    const float* __restrict__ ln_b, bf16* __restrict__ gel)
{
    const int tid = threadIdx.x;
    const int n0 = blockIdx.x * 32;
    const int b  = blockIdx.y;

    __shared__ float tile[384 * 33];
    __shared__ float ps[32 * 9], pq[32 * 9];
    __shared__ float mu_s[32], inv_s[32];

    const bf16* src = cvo + (size_t)b * 384 * 4096;
    for (int v = tid; v < 384 * 32; v += 256) {
        const int oc = v >> 5, nl = v & 31;
        tile[oc * 33 + nl] = bf2f(src[(size_t)oc * 4096 + n0 + nl]);
    }
    __syncthreads();

    {
        const int nl = tid & 31, sl = tid >> 5;
        float s = 0.f, q = 0.f;
        for (int oc = sl * 48; oc < sl * 48 + 48; ++oc) {
            const float xv = tile[oc * 33 + nl];
            s += xv; q += xv * xv;
        }
        ps[nl * 9 + sl] = s; pq[nl * 9 + sl] = q;
    }
    __syncthreads();
    if (tid < 32) {
        float s = 0.f, q = 0.f;
        for (int k = 0; k < 8; ++k) { s += ps[tid * 9 + k]; q += pq[tid * 9 + k]; }
        const float mu = s * (1.f / 384.f);
        const float var = q * (1.f / 384.f) - mu * mu;
        mu_s[tid] = mu; inv_s[tid] = rsqrtf(var + 1e-5f);
    }
    __syncthreads();

    for (int v = tid; v < 384 * 32; v += 256) {
        const int oc = v % 384, nl = v / 384;
        const float xv = tile[oc * 33 + nl];
        const float y = (xv - mu_s[nl]) * inv_s[nl] * ln_g[oc] + ln_b[oc];
        const float g = 0.5f * y * (1.f + erff(y * 0.70710678118f));
        gel[((size_t)b * 4096 + n0 + nl) * 384 + oc] = f2bf(g);
    }
}

// ---------------------------------------------------------------------------
extern "C" void kernel_launch(void* const* d_in, const int* in_sizes, int n_in,
                              void* d_out, int out_size, void* d_ws, size_t ws_size,
                              hipStream_t stream)
{
    const float* x      = (const float*)d_in[0];
    const float* q_w    = (const float*)d_in[1];
    const float* q_b    = (const float*)d_in[2];
    const float* kv_w   = (const float*)d_in[3];
    const float* kv_b   = (const float*)d_in[4];
    const float* fc_w   = (const float*)d_in[5];
    const float* fc_b   = (const float*)d_in[6];
    const float* dep_w  = (const float*)d_in[7];
    const float* dep_b  = (const float*)d_in[8];
    const float* ln_g   = (const float*)d_in[9];
    const float* ln_b   = (const float*)d_in[10];
    const float* proj_w = (const float*)d_in[11];
    const float* proj_b = (const float*)d_in[12];

    // workspace (total 152,174,592 B):
    char* ws = (char*)d_ws;
    bf16*  castspan = (bf16*)ws;                    // 26,345,472 B
    bf16*  xb     = castspan;
    bf16*  qwb    = castspan + 12582912;
    bf16*  kvwb   = castspan + 12730368;
    bf16*  projwb = castspan + 13025280;
    bf16*  qkv2   = (bf16*)(ws + 26345472);         // 75,497,472 B  [b][dd][t]
    bf16*  cvo    = (bf16*)(ws + 101842944);        // 25,165,824 B  [b][oc][n]
    bf16*  gel    = (bf16*)(ws + 127008768);        // 25,165,824 B  [b][n][c]

    // 0) fp32 -> bf16 cast of x and the GEMM weight matrices
    cast_kernel<<<dim3(12864), 256, 0, stream>>>(x, q_w, kv_w, proj_w, castspan);
    // 1) qkv2 = X @ [q_w;kv_w]^T + bias, transposed store [b][dd][t]
    //    (2304 blocks, XCD-swizzled: 9 n-tiles of each m-tile share an XCD)
    gemm_tile<0><<<dim3(2304), 256, 0, stream>>>(xb, qwb, kvwb, q_b, kv_b, qkv2);
    // 2) fused fc + grouped 3x3 conv -> bf16 [b][oc][n]
    fcconv_kernel<<<dim3(4, 64, 8), 256, 0, stream>>>(qkv2, fc_w, fc_b, dep_w,
                                                      dep_b, cvo);
    // 3) LayerNorm + exact GELU -> bf16 [b][n][c]
    ln_gelu_kernel<<<dim3(128, 8), 256, 0, stream>>>(cvo, ln_g, ln_b, gel);
    // 4) out = gelu @ proj_w^T + proj_b  (fp32 output; 768 blocks swizzled)
    gemm_tile<1><<<dim3(768), 256, 0, stream>>>(gel, projwb, nullptr, proj_b,
                                                nullptr, d_out);
}